// Round 11
// baseline (256.107 us; speedup 1.0000x reference)
//
#include <hip/hip_runtime.h>

// 2-layer tanh RNN, fused, f32, single-wave blocks, no barriers,
// single-buffer LDS state, SCALAR-PINNED weights. B=4096, T=512, H=20.
// R11 = R10 with the pin expressed on scalar floats (vector-type "+v"
// ties are unsupported: "tied indirect register inputs"). Each of the 60
// weight scalars is pinned via asm volatile("" : "+v"(s)) once before the
// loop -> opaque, non-rematerializable, VGPR-resident for the whole loop.
// Removes the 15 global_load_dwordx4 + vmcnt stalls per iteration that
// R1-R9 carried (VGPR stuck at 60-104 => weights reloaded every iter).

#define Bsz 4096
#define Tn  512
#define Hn  20
#define GB  3
#define XPAD 520               // x row stride: groups in distinct banks
#define NTHREADS 64

__device__ __forceinline__ float tanh_fast(float v) {
    // tanh(v) = 1 - 2/(exp(2v)+1); v_exp_f32 + v_rcp_f32.
    float e = __expf(2.0f * v);
    return 1.0f - 2.0f * __builtin_amdgcn_rcpf(e + 1.0f);
}

// 20-FMA dot against scalar weights WP_0..WP_19, two accumulator chains.
#define DOT20(acc, accb, WP, A0, A1, A2, A3, A4) do { \
    acc  = fmaf(WP##_0,  (A0).x, acc);  accb = fmaf(WP##_1,  (A0).y, accb); \
    acc  = fmaf(WP##_2,  (A0).z, acc);  accb = fmaf(WP##_3,  (A0).w, accb); \
    acc  = fmaf(WP##_4,  (A1).x, acc);  accb = fmaf(WP##_5,  (A1).y, accb); \
    acc  = fmaf(WP##_6,  (A1).z, acc);  accb = fmaf(WP##_7,  (A1).w, accb); \
    acc  = fmaf(WP##_8,  (A2).x, acc);  accb = fmaf(WP##_9,  (A2).y, accb); \
    acc  = fmaf(WP##_10, (A2).z, acc);  accb = fmaf(WP##_11, (A2).w, accb); \
    acc  = fmaf(WP##_12, (A3).x, acc);  accb = fmaf(WP##_13, (A3).y, accb); \
    acc  = fmaf(WP##_14, (A3).z, acc);  accb = fmaf(WP##_15, (A3).w, accb); \
    acc  = fmaf(WP##_16, (A4).x, acc);  accb = fmaf(WP##_17, (A4).y, accb); \
    acc  = fmaf(WP##_18, (A4).z, acc);  accb = fmaf(WP##_19, (A4).w, accb); \
} while (0)

#define LOAD_ROW(WP, ptr) \
    float WP##_0, WP##_1, WP##_2, WP##_3, WP##_4, WP##_5, WP##_6, WP##_7, \
          WP##_8, WP##_9, WP##_10, WP##_11, WP##_12, WP##_13, WP##_14,    \
          WP##_15, WP##_16, WP##_17, WP##_18, WP##_19;                    \
    { const float4* _p = (const float4*)(ptr);                            \
      float4 _t;                                                          \
      _t = _p[0]; WP##_0  = _t.x; WP##_1  = _t.y; WP##_2  = _t.z; WP##_3  = _t.w; \
      _t = _p[1]; WP##_4  = _t.x; WP##_5  = _t.y; WP##_6  = _t.z; WP##_7  = _t.w; \
      _t = _p[2]; WP##_8  = _t.x; WP##_9  = _t.y; WP##_10 = _t.z; WP##_11 = _t.w; \
      _t = _p[3]; WP##_12 = _t.x; WP##_13 = _t.y; WP##_14 = _t.z; WP##_15 = _t.w; \
      _t = _p[4]; WP##_16 = _t.x; WP##_17 = _t.y; WP##_18 = _t.z; WP##_19 = _t.w; }

#define PIN_ROW(WP) \
    asm volatile("" : "+v"(WP##_0), "+v"(WP##_1), "+v"(WP##_2), "+v"(WP##_3), \
                      "+v"(WP##_4), "+v"(WP##_5), "+v"(WP##_6), "+v"(WP##_7), \
                      "+v"(WP##_8), "+v"(WP##_9), "+v"(WP##_10), "+v"(WP##_11), \
                      "+v"(WP##_12), "+v"(WP##_13), "+v"(WP##_14), "+v"(WP##_15), \
                      "+v"(WP##_16), "+v"(WP##_17), "+v"(WP##_18), "+v"(WP##_19))

__global__ __launch_bounds__(NTHREADS, 1)
void rnn2_fused(const float* __restrict__ x,        // [B,T,1]
                const float* __restrict__ hidden,   // [2,B,H]
                const float* __restrict__ W_ih0,    // [H,1]
                const float* __restrict__ W_hh0,    // [H,H]
                const float* __restrict__ b_ih0,    // [H]
                const float* __restrict__ b_hh0,    // [H]
                const float* __restrict__ W_ih1,    // [H,H]
                const float* __restrict__ W_hh1,    // [H,H]
                const float* __restrict__ b_ih1,    // [H]
                const float* __restrict__ b_hh1,    // [H]
                const float* __restrict__ fc_w,     // [1,H]
                const float* __restrict__ fc_b,     // [1]
                float* __restrict__ out)            // [B] ++ [2,B,H] flat
{
    const int tid = threadIdx.x;
    int g = tid / Hn;                  // 0..3
    int j = tid - g * Hn;              // 0..19 (0..3 for tid>=60)
    const bool lane_ok = (tid < GB * Hn);
    if (!lane_ok) g = GB - 1;          // lanes 60..63 dup batch 2, j=0..3
                                       // (same-addr same-data writes: benign)
    const int  b        = blockIdx.x * GB + g;
    const bool b_ok     = (b < Bsz);
    const int  bl       = b_ok ? b : (Bsz - 1);
    const bool store_ok = lane_ok && b_ok;

    __shared__ float xs[GB][XPAD];     // 6.24 KB
    __shared__ float hs[2][GB][Hn];    // single-buffer state [layer][g][j]

    // ---- per-lane weight rows as 60 named scalars, PINNED to VGPRs
    LOAD_ROW(w0, W_hh0 + j * Hn)       // layer0 recurrent row j
    LOAD_ROW(w1, W_ih1 + j * Hn)       // layer1 input row j
    LOAD_ROW(w2, W_hh1 + j * Hn)       // layer1 recurrent row j

    const float wih0  = W_ih0[j];
    const float bias0 = b_ih0[j] + b_hh0[j];
    const float bias1 = b_ih1[j] + b_hh1[j];

    PIN_ROW(w0); PIN_ROW(w1); PIN_ROW(w2);

    // ---- stage ALL x (coalesced float4; clamped batch rows)
    {
        const int bB = blockIdx.x * GB;
        #pragma unroll
        for (int r = 0; r < (GB * Tn) / (NTHREADS * 4); ++r) {  // 6 rounds
            const int c  = (r * NTHREADS + tid) * 4;
            const int gg = c >> 9;            // c / 512
            const int t  = c & (Tn - 1);      // c % 512
            const int bb = (bB + gg < Bsz) ? (bB + gg) : (Bsz - 1);
            float4 v = *(const float4*)(x + (long)bb * Tn + t);
            *(float4*)&xs[gg][t] = v;
        }
    }

    // ---- init state: hs[0] = h0[-1], hs[1] = h1[-1]
    hs[0][g][j] = hidden[bl * Hn + j];
    hs[1][g][j] = hidden[(long)Bsz * Hn + bl * Hn + j];
    // single-wave in-order DS pipe: later reads see these writes

    // ---- prologue (i=0): h0[0] = tanh(W_hh0 h0[-1] + x0 wih0 + b0)
    {
        const float4 h00 = *(const float4*)&hs[0][g][0];
        const float4 h01 = *(const float4*)&hs[0][g][4];
        const float4 h02 = *(const float4*)&hs[0][g][8];
        const float4 h03 = *(const float4*)&hs[0][g][12];
        const float4 h04 = *(const float4*)&hs[0][g][16];
        float a0 = fmaf(xs[g][0], wih0, bias0), a0b = 0.f;
        DOT20(a0, a0b, w0, h00, h01, h02, h03, h04);
        hs[0][g][j] = tanh_fast(a0 + a0b);
    }

    // ---- main loop i=1..511: entry: hs[0]=h0[i-1], hs[1]=h1[i-2].
    // computes h0[i], h1[i-1]; writes both. Rolled, branchless.
    #pragma unroll 1
    for (int i = 1; i < Tn; ++i) {
        const float4 h00 = *(const float4*)&hs[0][g][0];
        const float4 h01 = *(const float4*)&hs[0][g][4];
        const float4 h02 = *(const float4*)&hs[0][g][8];
        const float4 h03 = *(const float4*)&hs[0][g][12];
        const float4 h04 = *(const float4*)&hs[0][g][16];
        const float4 h10 = *(const float4*)&hs[1][g][0];
        const float4 h11 = *(const float4*)&hs[1][g][4];
        const float4 h12 = *(const float4*)&hs[1][g][8];
        const float4 h13 = *(const float4*)&hs[1][g][12];
        const float4 h14 = *(const float4*)&hs[1][g][16];

        const float xt = xs[g][i];

        float a0 = fmaf(xt, wih0, bias0), a0b = 0.f;
        float a1 = bias1,                 a1b = 0.f;
        float a2 = 0.f,                   a2b = 0.f;
        DOT20(a0, a0b, w0, h00, h01, h02, h03, h04);
        DOT20(a1, a1b, w1, h00, h01, h02, h03, h04);
        DOT20(a2, a2b, w2, h10, h11, h12, h13, h14);

        const float n0 = tanh_fast(a0 + a0b);
        const float n1 = tanh_fast((a1 + a1b) + (a2 + a2b));
        hs[0][g][j] = n0;   // h0[i]
        hs[1][g][j] = n1;   // h1[i-1]
    }

    // ---- epilogue (i=512): h1[511] from h0[511], h1[510]
    {
        const float4 h00 = *(const float4*)&hs[0][g][0];
        const float4 h01 = *(const float4*)&hs[0][g][4];
        const float4 h02 = *(const float4*)&hs[0][g][8];
        const float4 h03 = *(const float4*)&hs[0][g][12];
        const float4 h04 = *(const float4*)&hs[0][g][16];
        const float4 h10 = *(const float4*)&hs[1][g][0];
        const float4 h11 = *(const float4*)&hs[1][g][4];
        const float4 h12 = *(const float4*)&hs[1][g][8];
        const float4 h13 = *(const float4*)&hs[1][g][12];
        const float4 h14 = *(const float4*)&hs[1][g][16];
        float a1 = bias1, a1b = 0.f, a2 = 0.f, a2b = 0.f;
        DOT20(a1, a1b, w1, h00, h01, h02, h03, h04);
        DOT20(a2, a2b, w2, h10, h11, h12, h13, h14);
        hs[1][g][j] = tanh_fast((a1 + a1b) + (a2 + a2b));
    }

    // ---- outputs: hs[0]=h0[511], hs[1]=h1[511]
    if (store_ok) {
        out[Bsz + (long)b * Hn + j]                  = hs[0][g][j];  // new_hidden[0]
        out[Bsz + (long)Bsz * Hn + (long)b * Hn + j] = hs[1][g][j];  // new_hidden[1]
        if (j == 0) {                  // fc head: one lane per batch
            const float4 f0 = ((const float4*)fc_w)[0];
            const float4 f1 = ((const float4*)fc_w)[1];
            const float4 f2 = ((const float4*)fc_w)[2];
            const float4 f3 = ((const float4*)fc_w)[3];
            const float4 f4 = ((const float4*)fc_w)[4];
            const float4 v0 = *(const float4*)&hs[1][g][0];
            const float4 v1 = *(const float4*)&hs[1][g][4];
            const float4 v2 = *(const float4*)&hs[1][g][8];
            const float4 v3 = *(const float4*)&hs[1][g][12];
            const float4 v4 = *(const float4*)&hs[1][g][16];
            float accA = fc_b[0], accB = 0.f;
            accA = fmaf(f0.x, v0.x, accA); accB = fmaf(f0.y, v0.y, accB);
            accA = fmaf(f0.z, v0.z, accA); accB = fmaf(f0.w, v0.w, accB);
            accA = fmaf(f1.x, v1.x, accA); accB = fmaf(f1.y, v1.y, accB);
            accA = fmaf(f1.z, v1.z, accA); accB = fmaf(f1.w, v1.w, accB);
            accA = fmaf(f2.x, v2.x, accA); accB = fmaf(f2.y, v2.y, accB);
            accA = fmaf(f2.z, v2.z, accA); accB = fmaf(f2.w, v2.w, accB);
            accA = fmaf(f3.x, v3.x, accA); accB = fmaf(f3.y, v3.y, accB);
            accA = fmaf(f3.z, v3.z, accA); accB = fmaf(f3.w, v3.w, accB);
            accA = fmaf(f4.x, v4.x, accA); accB = fmaf(f4.y, v4.y, accB);
            accA = fmaf(f4.z, v4.z, accA); accB = fmaf(f4.w, v4.w, accB);
            out[b] = accA + accB;
        }
    }
}

extern "C" void kernel_launch(void* const* d_in, const int* in_sizes, int n_in,
                              void* d_out, int out_size, void* d_ws, size_t ws_size,
                              hipStream_t stream) {
    const float* x      = (const float*)d_in[0];
    const float* hidden = (const float*)d_in[1];
    const float* W_ih0  = (const float*)d_in[2];
    const float* W_hh0  = (const float*)d_in[3];
    const float* b_ih0  = (const float*)d_in[4];
    const float* b_hh0  = (const float*)d_in[5];
    const float* W_ih1  = (const float*)d_in[6];
    const float* W_hh1  = (const float*)d_in[7];
    const float* b_ih1  = (const float*)d_in[8];
    const float* b_hh1  = (const float*)d_in[9];
    const float* fc_w   = (const float*)d_in[10];
    const float* fc_b   = (const float*)d_in[11];

    const int nblocks = (Bsz + GB - 1) / GB;   // 1366
    rnn2_fused<<<nblocks, NTHREADS, 0, stream>>>(
        x, hidden, W_ih0, W_hh0, b_ih0, b_hh0,
        W_ih1, W_hh1, b_ih1, b_hh1, fc_w, fc_b, (float*)d_out);
}

// Round 12
// 146.882 us; speedup vs baseline: 1.7436x; 1.7436x over previous
//
#include <hip/hip_runtime.h>

// 2-layer tanh RNN, fused, f32, single-wave blocks, no barriers,
// single-buffer LDS state. B=4096, T=512, H=20. GB=3 batches/wave.
// R12 key change: __attribute__((amdgpu_waves_per_eu(1,2))).
//   R6-R11 post-mortems: the register allocator works to an occupancy-
//   driven VGPR budget (observed VGPR_Count 44-104) and refuses to keep
//   the 60 loop-invariant weight scalars resident -- it reloads them from
//   global (L1-hit) every iteration (~15 loads + vmcnt stalls/iter), and
//   when pinned (R11) it spills them to scratch instead (256us).
//   waves_per_eu max=2 => explicit VGPR budget 256/wave (need ~130),
//   while still permitting 8 waves/CU at runtime (we need 5.33).
// Weights as 60 named scalar SSA values (no arrays -> no SROA issues).

#define Bsz 4096
#define Tn  512
#define Hn  20
#define GB  3
#define XPAD 520               // x row stride: groups 8 banks apart
#define NTHREADS 64

__device__ __forceinline__ float tanh_fast(float v) {
    // tanh(v) = 1 - 2/(exp(2v)+1); v_exp_f32 + v_rcp_f32.
    float e = __expf(2.0f * v);
    return 1.0f - 2.0f * __builtin_amdgcn_rcpf(e + 1.0f);
}

// 20-FMA dot against scalar weights WP_0..WP_19, two accumulator chains.
#define DOT20(acc, accb, WP, A0, A1, A2, A3, A4) do { \
    acc  = fmaf(WP##_0,  (A0).x, acc);  accb = fmaf(WP##_1,  (A0).y, accb); \
    acc  = fmaf(WP##_2,  (A0).z, acc);  accb = fmaf(WP##_3,  (A0).w, accb); \
    acc  = fmaf(WP##_4,  (A1).x, acc);  accb = fmaf(WP##_5,  (A1).y, accb); \
    acc  = fmaf(WP##_6,  (A1).z, acc);  accb = fmaf(WP##_7,  (A1).w, accb); \
    acc  = fmaf(WP##_8,  (A2).x, acc);  accb = fmaf(WP##_9,  (A2).y, accb); \
    acc  = fmaf(WP##_10, (A2).z, acc);  accb = fmaf(WP##_11, (A2).w, accb); \
    acc  = fmaf(WP##_12, (A3).x, acc);  accb = fmaf(WP##_13, (A3).y, accb); \
    acc  = fmaf(WP##_14, (A3).z, acc);  accb = fmaf(WP##_15, (A3).w, accb); \
    acc  = fmaf(WP##_16, (A4).x, acc);  accb = fmaf(WP##_17, (A4).y, accb); \
    acc  = fmaf(WP##_18, (A4).z, acc);  accb = fmaf(WP##_19, (A4).w, accb); \
} while (0)

#define LOAD_ROW(WP, ptr) \
    float WP##_0, WP##_1, WP##_2, WP##_3, WP##_4, WP##_5, WP##_6, WP##_7, \
          WP##_8, WP##_9, WP##_10, WP##_11, WP##_12, WP##_13, WP##_14,    \
          WP##_15, WP##_16, WP##_17, WP##_18, WP##_19;                    \
    { const float4* _p = (const float4*)(ptr);                            \
      float4 _t;                                                          \
      _t = _p[0]; WP##_0  = _t.x; WP##_1  = _t.y; WP##_2  = _t.z; WP##_3  = _t.w; \
      _t = _p[1]; WP##_4  = _t.x; WP##_5  = _t.y; WP##_6  = _t.z; WP##_7  = _t.w; \
      _t = _p[2]; WP##_8  = _t.x; WP##_9  = _t.y; WP##_10 = _t.z; WP##_11 = _t.w; \
      _t = _p[3]; WP##_12 = _t.x; WP##_13 = _t.y; WP##_14 = _t.z; WP##_15 = _t.w; \
      _t = _p[4]; WP##_16 = _t.x; WP##_17 = _t.y; WP##_18 = _t.z; WP##_19 = _t.w; }

__global__ __launch_bounds__(NTHREADS)
__attribute__((amdgpu_waves_per_eu(1, 2)))
void rnn2_fused(const float* __restrict__ x,        // [B,T,1]
                const float* __restrict__ hidden,   // [2,B,H]
                const float* __restrict__ W_ih0,    // [H,1]
                const float* __restrict__ W_hh0,    // [H,H]
                const float* __restrict__ b_ih0,    // [H]
                const float* __restrict__ b_hh0,    // [H]
                const float* __restrict__ W_ih1,    // [H,H]
                const float* __restrict__ W_hh1,    // [H,H]
                const float* __restrict__ b_ih1,    // [H]
                const float* __restrict__ b_hh1,    // [H]
                const float* __restrict__ fc_w,     // [1,H]
                const float* __restrict__ fc_b,     // [1]
                float* __restrict__ out)            // [B] ++ [2,B,H] flat
{
    const int tid = threadIdx.x;
    int g = tid / Hn;                  // 0..3
    int j = tid - g * Hn;              // 0..19 (0..3 for tid>=60)
    const bool lane_ok = (tid < GB * Hn);
    if (!lane_ok) g = GB - 1;          // lanes 60..63 dup batch 2, j=0..3
                                       // (same-addr same-data writes: benign)
    const int  b        = blockIdx.x * GB + g;
    const bool b_ok     = (b < Bsz);
    const int  bl       = b_ok ? b : (Bsz - 1);
    const bool store_ok = lane_ok && b_ok;

    __shared__ float xs[GB][XPAD];     // 6.24 KB
    __shared__ float hs[2][GB][Hn];    // single-buffer state [layer][g][j]

    // ---- per-lane weight rows as 60 named scalars (loop-invariant)
    LOAD_ROW(w0, W_hh0 + j * Hn)       // layer0 recurrent row j
    LOAD_ROW(w1, W_ih1 + j * Hn)       // layer1 input row j
    LOAD_ROW(w2, W_hh1 + j * Hn)       // layer1 recurrent row j

    const float wih0  = W_ih0[j];
    const float bias0 = b_ih0[j] + b_hh0[j];
    const float bias1 = b_ih1[j] + b_hh1[j];

    // ---- stage ALL x (coalesced float4; clamped batch rows)
    {
        const int bB = blockIdx.x * GB;
        #pragma unroll
        for (int r = 0; r < (GB * Tn) / (NTHREADS * 4); ++r) {  // 6 rounds
            const int c  = (r * NTHREADS + tid) * 4;
            const int gg = c >> 9;            // c / 512
            const int t  = c & (Tn - 1);      // c % 512
            const int bb = (bB + gg < Bsz) ? (bB + gg) : (Bsz - 1);
            float4 v = *(const float4*)(x + (long)bb * Tn + t);
            *(float4*)&xs[gg][t] = v;
        }
    }

    // ---- init state: hs[0] = h0[-1], hs[1] = h1[-1]
    hs[0][g][j] = hidden[bl * Hn + j];
    hs[1][g][j] = hidden[(long)Bsz * Hn + bl * Hn + j];
    // single-wave in-order DS pipe: later reads see these writes

    // ---- prologue (i=0): h0[0] = tanh(W_hh0 h0[-1] + x0 wih0 + b0)
    {
        const float4 h00 = *(const float4*)&hs[0][g][0];
        const float4 h01 = *(const float4*)&hs[0][g][4];
        const float4 h02 = *(const float4*)&hs[0][g][8];
        const float4 h03 = *(const float4*)&hs[0][g][12];
        const float4 h04 = *(const float4*)&hs[0][g][16];
        float a0 = fmaf(xs[g][0], wih0, bias0), a0b = 0.f;
        DOT20(a0, a0b, w0, h00, h01, h02, h03, h04);
        hs[0][g][j] = tanh_fast(a0 + a0b);
    }

    // ---- main loop i=1..511: entry: hs[0]=h0[i-1], hs[1]=h1[i-2].
    // computes h0[i], h1[i-1]; writes both. Rolled, branchless.
    #pragma unroll 1
    for (int i = 1; i < Tn; ++i) {
        const float4 h00 = *(const float4*)&hs[0][g][0];
        const float4 h01 = *(const float4*)&hs[0][g][4];
        const float4 h02 = *(const float4*)&hs[0][g][8];
        const float4 h03 = *(const float4*)&hs[0][g][12];
        const float4 h04 = *(const float4*)&hs[0][g][16];
        const float4 h10 = *(const float4*)&hs[1][g][0];
        const float4 h11 = *(const float4*)&hs[1][g][4];
        const float4 h12 = *(const float4*)&hs[1][g][8];
        const float4 h13 = *(const float4*)&hs[1][g][12];
        const float4 h14 = *(const float4*)&hs[1][g][16];

        const float xt = xs[g][i];

        float a0 = fmaf(xt, wih0, bias0), a0b = 0.f;
        float a1 = bias1,                 a1b = 0.f;
        float a2 = 0.f,                   a2b = 0.f;
        DOT20(a0, a0b, w0, h00, h01, h02, h03, h04);
        DOT20(a1, a1b, w1, h00, h01, h02, h03, h04);
        DOT20(a2, a2b, w2, h10, h11, h12, h13, h14);

        const float n0 = tanh_fast(a0 + a0b);
        const float n1 = tanh_fast((a1 + a1b) + (a2 + a2b));
        hs[0][g][j] = n0;   // h0[i]
        hs[1][g][j] = n1;   // h1[i-1]
    }

    // ---- epilogue (i=512): h1[511] from h0[511], h1[510]
    {
        const float4 h00 = *(const float4*)&hs[0][g][0];
        const float4 h01 = *(const float4*)&hs[0][g][4];
        const float4 h02 = *(const float4*)&hs[0][g][8];
        const float4 h03 = *(const float4*)&hs[0][g][12];
        const float4 h04 = *(const float4*)&hs[0][g][16];
        const float4 h10 = *(const float4*)&hs[1][g][0];
        const float4 h11 = *(const float4*)&hs[1][g][4];
        const float4 h12 = *(const float4*)&hs[1][g][8];
        const float4 h13 = *(const float4*)&hs[1][g][12];
        const float4 h14 = *(const float4*)&hs[1][g][16];
        float a1 = bias1, a1b = 0.f, a2 = 0.f, a2b = 0.f;
        DOT20(a1, a1b, w1, h00, h01, h02, h03, h04);
        DOT20(a2, a2b, w2, h10, h11, h12, h13, h14);
        hs[1][g][j] = tanh_fast((a1 + a1b) + (a2 + a2b));
    }

    // ---- outputs: hs[0]=h0[511], hs[1]=h1[511]
    if (store_ok) {
        out[Bsz + (long)b * Hn + j]                  = hs[0][g][j];  // new_hidden[0]
        out[Bsz + (long)Bsz * Hn + (long)b * Hn + j] = hs[1][g][j];  // new_hidden[1]
        if (j == 0) {                  // fc head: one lane per batch
            const float4 f0 = ((const float4*)fc_w)[0];
            const float4 f1 = ((const float4*)fc_w)[1];
            const float4 f2 = ((const float4*)fc_w)[2];
            const float4 f3 = ((const float4*)fc_w)[3];
            const float4 f4 = ((const float4*)fc_w)[4];
            const float4 v0 = *(const float4*)&hs[1][g][0];
            const float4 v1 = *(const float4*)&hs[1][g][4];
            const float4 v2 = *(const float4*)&hs[1][g][8];
            const float4 v3 = *(const float4*)&hs[1][g][12];
            const float4 v4 = *(const float4*)&hs[1][g][16];
            float accA = fc_b[0], accB = 0.f;
            accA = fmaf(f0.x, v0.x, accA); accB = fmaf(f0.y, v0.y, accB);
            accA = fmaf(f0.z, v0.z, accA); accB = fmaf(f0.w, v0.w, accB);
            accA = fmaf(f1.x, v1.x, accA); accB = fmaf(f1.y, v1.y, accB);
            accA = fmaf(f1.z, v1.z, accA); accB = fmaf(f1.w, v1.w, accB);
            accA = fmaf(f2.x, v2.x, accA); accB = fmaf(f2.y, v2.y, accB);
            accA = fmaf(f2.z, v2.z, accA); accB = fmaf(f2.w, v2.w, accB);
            accA = fmaf(f3.x, v3.x, accA); accB = fmaf(f3.y, v3.y, accB);
            accA = fmaf(f3.z, v3.z, accA); accB = fmaf(f3.w, v3.w, accB);
            accA = fmaf(f4.x, v4.x, accA); accB = fmaf(f4.y, v4.y, accB);
            accA = fmaf(f4.z, v4.z, accA); accB = fmaf(f4.w, v4.w, accB);
            out[b] = accA + accB;
        }
    }
}

extern "C" void kernel_launch(void* const* d_in, const int* in_sizes, int n_in,
                              void* d_out, int out_size, void* d_ws, size_t ws_size,
                              hipStream_t stream) {
    const float* x      = (const float*)d_in[0];
    const float* hidden = (const float*)d_in[1];
    const float* W_ih0  = (const float*)d_in[2];
    const float* W_hh0  = (const float*)d_in[3];
    const float* b_ih0  = (const float*)d_in[4];
    const float* b_hh0  = (const float*)d_in[5];
    const float* W_ih1  = (const float*)d_in[6];
    const float* W_hh1  = (const float*)d_in[7];
    const float* b_ih1  = (const float*)d_in[8];
    const float* b_hh1  = (const float*)d_in[9];
    const float* fc_w   = (const float*)d_in[10];
    const float* fc_b   = (const float*)d_in[11];

    const int nblocks = (Bsz + GB - 1) / GB;   // 1366
    rnn2_fused<<<nblocks, NTHREADS, 0, stream>>>(
        x, hidden, W_ih0, W_hh0, b_ih0, b_hh0,
        W_ih1, W_hh1, b_ih1, b_hh1, fc_w, fc_b, (float*)d_out);
}

// Round 13
// 141.618 us; speedup vs baseline: 1.8084x; 1.0372x over previous
//
#include <hip/hip_runtime.h>

// 2-layer tanh RNN, fused, f32, single-wave blocks, no barriers,
// single-buffer LDS state, PACKED-f32 math. B=4096, T=512, H=20.
// R13 = R12 (146.9us, waves_per_eu(1,2) -> RA budget 256) + v_pk_fma_f32:
//   R12 is VALU-issue-bound (VALUBusy 60% at 1.33 waves/SIMD). The 60
//   scalar FMAs per iter become 30 packed f32x2 FMAs via
//   __builtin_elementwise_fma on ext_vector_type(2) (VOP3P v_pk_fma_f32).

#define Bsz 4096
#define Tn  512
#define Hn  20
#define GB  3
#define XPAD 520               // x row stride: groups 8 banks apart
#define NTHREADS 64

typedef float v2 __attribute__((ext_vector_type(2)));

__device__ __forceinline__ float tanh_fast(float v) {
    // tanh(v) = 1 - 2/(exp(2v)+1); v_exp_f32 + v_rcp_f32.
    float e = __expf(2.0f * v);
    return 1.0f - 2.0f * __builtin_amdgcn_rcpf(e + 1.0f);
}

// packed 20-dot: 10 v_pk_fma_f32 over two packed accumulator chains.
#define DOT20P(acc, accb, W, H) do { \
    acc  = __builtin_elementwise_fma(W##0, H##0, acc);  \
    accb = __builtin_elementwise_fma(W##1, H##1, accb); \
    acc  = __builtin_elementwise_fma(W##2, H##2, acc);  \
    accb = __builtin_elementwise_fma(W##3, H##3, accb); \
    acc  = __builtin_elementwise_fma(W##4, H##4, acc);  \
    accb = __builtin_elementwise_fma(W##5, H##5, accb); \
    acc  = __builtin_elementwise_fma(W##6, H##6, acc);  \
    accb = __builtin_elementwise_fma(W##7, H##7, accb); \
    acc  = __builtin_elementwise_fma(W##8, H##8, acc);  \
    accb = __builtin_elementwise_fma(W##9, H##9, accb); \
} while (0)

// load one H=20 row as 10 named v2 SSA values (via float4 vector loads)
#define LOAD_ROWP(W, ptr) \
    v2 W##0, W##1, W##2, W##3, W##4, W##5, W##6, W##7, W##8, W##9; \
    { const float4* _p = (const float4*)(ptr); \
      float4 _t; \
      _t = _p[0]; W##0 = (v2){_t.x, _t.y}; W##1 = (v2){_t.z, _t.w}; \
      _t = _p[1]; W##2 = (v2){_t.x, _t.y}; W##3 = (v2){_t.z, _t.w}; \
      _t = _p[2]; W##4 = (v2){_t.x, _t.y}; W##5 = (v2){_t.z, _t.w}; \
      _t = _p[3]; W##6 = (v2){_t.x, _t.y}; W##7 = (v2){_t.z, _t.w}; \
      _t = _p[4]; W##8 = (v2){_t.x, _t.y}; W##9 = (v2){_t.z, _t.w}; }

// read h-state tile (LDS, broadcast b128) into 10 named v2 values
#define READ_H(H, base) \
    v2 H##0, H##1, H##2, H##3, H##4, H##5, H##6, H##7, H##8, H##9; \
    { const float4 _a = *(const float4*)((base) + 0);  \
      const float4 _b = *(const float4*)((base) + 4);  \
      const float4 _c = *(const float4*)((base) + 8);  \
      const float4 _d = *(const float4*)((base) + 12); \
      const float4 _e = *(const float4*)((base) + 16); \
      H##0 = (v2){_a.x, _a.y}; H##1 = (v2){_a.z, _a.w}; \
      H##2 = (v2){_b.x, _b.y}; H##3 = (v2){_b.z, _b.w}; \
      H##4 = (v2){_c.x, _c.y}; H##5 = (v2){_c.z, _c.w}; \
      H##6 = (v2){_d.x, _d.y}; H##7 = (v2){_d.z, _d.w}; \
      H##8 = (v2){_e.x, _e.y}; H##9 = (v2){_e.z, _e.w}; }

__global__ __launch_bounds__(NTHREADS)
__attribute__((amdgpu_waves_per_eu(1, 2)))
void rnn2_fused(const float* __restrict__ x,        // [B,T,1]
                const float* __restrict__ hidden,   // [2,B,H]
                const float* __restrict__ W_ih0,    // [H,1]
                const float* __restrict__ W_hh0,    // [H,H]
                const float* __restrict__ b_ih0,    // [H]
                const float* __restrict__ b_hh0,    // [H]
                const float* __restrict__ W_ih1,    // [H,H]
                const float* __restrict__ W_hh1,    // [H,H]
                const float* __restrict__ b_ih1,    // [H]
                const float* __restrict__ b_hh1,    // [H]
                const float* __restrict__ fc_w,     // [1,H]
                const float* __restrict__ fc_b,     // [1]
                float* __restrict__ out)            // [B] ++ [2,B,H] flat
{
    const int tid = threadIdx.x;
    int g = tid / Hn;                  // 0..3
    int j = tid - g * Hn;              // 0..19 (0..3 for tid>=60)
    const bool lane_ok = (tid < GB * Hn);
    if (!lane_ok) g = GB - 1;          // lanes 60..63 dup batch 2, j=0..3
                                       // (same-addr same-data writes: benign)
    const int  b        = blockIdx.x * GB + g;
    const bool b_ok     = (b < Bsz);
    const int  bl       = b_ok ? b : (Bsz - 1);
    const bool store_ok = lane_ok && b_ok;

    __shared__ float xs[GB][XPAD];     // 6.24 KB
    __shared__ float hs[2][GB][Hn];    // single-buffer state [layer][g][j]

    // ---- per-lane weight rows as 30 named v2 SSA values (loop-invariant)
    LOAD_ROWP(w0, W_hh0 + j * Hn)      // layer0 recurrent row j
    LOAD_ROWP(w1, W_ih1 + j * Hn)      // layer1 input row j
    LOAD_ROWP(w2, W_hh1 + j * Hn)      // layer1 recurrent row j

    const float wih0  = W_ih0[j];
    const float bias0 = b_ih0[j] + b_hh0[j];
    const float bias1 = b_ih1[j] + b_hh1[j];

    // ---- stage ALL x (coalesced float4; clamped batch rows)
    {
        const int bB = blockIdx.x * GB;
        #pragma unroll
        for (int r = 0; r < (GB * Tn) / (NTHREADS * 4); ++r) {  // 6 rounds
            const int c  = (r * NTHREADS + tid) * 4;
            const int gg = c >> 9;            // c / 512
            const int t  = c & (Tn - 1);      // c % 512
            const int bb = (bB + gg < Bsz) ? (bB + gg) : (Bsz - 1);
            float4 v = *(const float4*)(x + (long)bb * Tn + t);
            *(float4*)&xs[gg][t] = v;
        }
    }

    // ---- init state: hs[0] = h0[-1], hs[1] = h1[-1]
    hs[0][g][j] = hidden[bl * Hn + j];
    hs[1][g][j] = hidden[(long)Bsz * Hn + bl * Hn + j];
    // single-wave in-order DS pipe: later reads see these writes

    // ---- prologue (i=0): h0[0] = tanh(W_hh0 h0[-1] + x0 wih0 + b0)
    {
        READ_H(hA, &hs[0][g][0])
        v2 a0  = (v2){fmaf(xs[g][0], wih0, bias0), 0.f};
        v2 a0b = (v2){0.f, 0.f};
        DOT20P(a0, a0b, w0, hA);
        v2 s0 = a0 + a0b;
        hs[0][g][j] = tanh_fast(s0.x + s0.y);
    }

    // ---- main loop i=1..511: entry: hs[0]=h0[i-1], hs[1]=h1[i-2].
    // computes h0[i], h1[i-1]; writes both. Rolled, branchless.
    #pragma unroll 1
    for (int i = 1; i < Tn; ++i) {
        READ_H(hA, &hs[0][g][0])
        READ_H(hB, &hs[1][g][0])

        const float xt = xs[g][i];

        v2 a0  = (v2){fmaf(xt, wih0, bias0), 0.f};
        v2 a0b = (v2){0.f, 0.f};
        v2 a1  = (v2){bias1, 0.f};
        v2 a1b = (v2){0.f, 0.f};
        v2 a2  = (v2){0.f, 0.f};
        v2 a2b = (v2){0.f, 0.f};
        DOT20P(a0, a0b, w0, hA);
        DOT20P(a1, a1b, w1, hA);
        DOT20P(a2, a2b, w2, hB);

        const v2 s0 = a0 + a0b;
        const v2 s1 = (a1 + a1b) + (a2 + a2b);
        const float n0 = tanh_fast(s0.x + s0.y);
        const float n1 = tanh_fast(s1.x + s1.y);
        hs[0][g][j] = n0;   // h0[i]
        hs[1][g][j] = n1;   // h1[i-1]
    }

    // ---- epilogue (i=512): h1[511] from h0[511], h1[510]
    {
        READ_H(hA, &hs[0][g][0])
        READ_H(hB, &hs[1][g][0])
        v2 a1  = (v2){bias1, 0.f};
        v2 a1b = (v2){0.f, 0.f};
        v2 a2  = (v2){0.f, 0.f};
        v2 a2b = (v2){0.f, 0.f};
        DOT20P(a1, a1b, w1, hA);
        DOT20P(a2, a2b, w2, hB);
        const v2 s1 = (a1 + a1b) + (a2 + a2b);
        hs[1][g][j] = tanh_fast(s1.x + s1.y);
    }

    // ---- outputs: hs[0]=h0[511], hs[1]=h1[511]
    if (store_ok) {
        out[Bsz + (long)b * Hn + j]                  = hs[0][g][j];  // new_hidden[0]
        out[Bsz + (long)Bsz * Hn + (long)b * Hn + j] = hs[1][g][j];  // new_hidden[1]
        if (j == 0) {                  // fc head: one lane per batch
            LOAD_ROWP(fw, fc_w)
            READ_H(hv, &hs[1][g][0])
            v2 aA = (v2){fc_b[0], 0.f};
            v2 aB = (v2){0.f, 0.f};
            DOT20P(aA, aB, fw, hv);
            const v2 s = aA + aB;
            out[b] = s.x + s.y;
        }
    }
}

extern "C" void kernel_launch(void* const* d_in, const int* in_sizes, int n_in,
                              void* d_out, int out_size, void* d_ws, size_t ws_size,
                              hipStream_t stream) {
    const float* x      = (const float*)d_in[0];
    const float* hidden = (const float*)d_in[1];
    const float* W_ih0  = (const float*)d_in[2];
    const float* W_hh0  = (const float*)d_in[3];
    const float* b_ih0  = (const float*)d_in[4];
    const float* b_hh0  = (const float*)d_in[5];
    const float* W_ih1  = (const float*)d_in[6];
    const float* W_hh1  = (const float*)d_in[7];
    const float* b_ih1  = (const float*)d_in[8];
    const float* b_hh1  = (const float*)d_in[9];
    const float* fc_w   = (const float*)d_in[10];
    const float* fc_b   = (const float*)d_in[11];

    const int nblocks = (Bsz + GB - 1) / GB;   // 1366
    rnn2_fused<<<nblocks, NTHREADS, 0, stream>>>(
        x, hidden, W_ih0, W_hh0, b_ih0, b_hh0,
        W_ih1, W_hh1, b_ih1, b_hh1, fc_w, fc_b, (float*)d_out);
}

// Round 14
// 129.447 us; speedup vs baseline: 1.9785x; 1.0940x over previous
//
#include <hip/hip_runtime.h>

// 2-layer tanh RNN, fused, f32, single-wave blocks, no barriers,
// single-buffer LDS state, packed-f32 math, UNROLL-4 software pipeline.
// B=4096, T=512, H=20. GB=3 batches/wave.
// R14 = R13 (141.6us) with #pragma unroll 4:
//   R13 is latency-bound on the per-iter serial chain (663cyc/iter vs
//   ~300cyc true deps; VALUBusy 40%). Only layer0 is truly serial;
//   layer1 has a full iteration of slack. Unrolling gives the scheduler
//   a cross-iteration window: iter i+1's ds_reads issue behind iter i's
//   ds_write (in-order DS pipe => pipelined), overlapping read latency
//   with layer1/tanh compute. waves_per_eu(1,2) keeps RA budget at 256
//   so the wider window doesn't spill (R8's unroll failure predated it).

#define Bsz 4096
#define Tn  512
#define Hn  20
#define GB  3
#define XPAD 520               // x row stride: groups 8 banks apart
#define NTHREADS 64

typedef float v2 __attribute__((ext_vector_type(2)));

__device__ __forceinline__ float tanh_fast(float v) {
    // tanh(v) = 1 - 2/(exp(2v)+1); v_exp_f32 + v_rcp_f32.
    float e = __expf(2.0f * v);
    return 1.0f - 2.0f * __builtin_amdgcn_rcpf(e + 1.0f);
}

// packed 20-dot: 10 v_pk_fma_f32 over two packed accumulator chains.
#define DOT20P(acc, accb, W, H) do { \
    acc  = __builtin_elementwise_fma(W##0, H##0, acc);  \
    accb = __builtin_elementwise_fma(W##1, H##1, accb); \
    acc  = __builtin_elementwise_fma(W##2, H##2, acc);  \
    accb = __builtin_elementwise_fma(W##3, H##3, accb); \
    acc  = __builtin_elementwise_fma(W##4, H##4, acc);  \
    accb = __builtin_elementwise_fma(W##5, H##5, accb); \
    acc  = __builtin_elementwise_fma(W##6, H##6, acc);  \
    accb = __builtin_elementwise_fma(W##7, H##7, accb); \
    acc  = __builtin_elementwise_fma(W##8, H##8, acc);  \
    accb = __builtin_elementwise_fma(W##9, H##9, accb); \
} while (0)

// load one H=20 row as 10 named v2 SSA values (via float4 vector loads)
#define LOAD_ROWP(W, ptr) \
    v2 W##0, W##1, W##2, W##3, W##4, W##5, W##6, W##7, W##8, W##9; \
    { const float4* _p = (const float4*)(ptr); \
      float4 _t; \
      _t = _p[0]; W##0 = (v2){_t.x, _t.y}; W##1 = (v2){_t.z, _t.w}; \
      _t = _p[1]; W##2 = (v2){_t.x, _t.y}; W##3 = (v2){_t.z, _t.w}; \
      _t = _p[2]; W##4 = (v2){_t.x, _t.y}; W##5 = (v2){_t.z, _t.w}; \
      _t = _p[3]; W##6 = (v2){_t.x, _t.y}; W##7 = (v2){_t.z, _t.w}; \
      _t = _p[4]; W##8 = (v2){_t.x, _t.y}; W##9 = (v2){_t.z, _t.w}; }

// read h-state tile (LDS, broadcast b128) into 10 named v2 values
#define READ_H(H, base) \
    v2 H##0, H##1, H##2, H##3, H##4, H##5, H##6, H##7, H##8, H##9; \
    { const float4 _a = *(const float4*)((base) + 0);  \
      const float4 _b = *(const float4*)((base) + 4);  \
      const float4 _c = *(const float4*)((base) + 8);  \
      const float4 _d = *(const float4*)((base) + 12); \
      const float4 _e = *(const float4*)((base) + 16); \
      H##0 = (v2){_a.x, _a.y}; H##1 = (v2){_a.z, _a.w}; \
      H##2 = (v2){_b.x, _b.y}; H##3 = (v2){_b.z, _b.w}; \
      H##4 = (v2){_c.x, _c.y}; H##5 = (v2){_c.z, _c.w}; \
      H##6 = (v2){_d.x, _d.y}; H##7 = (v2){_d.z, _d.w}; \
      H##8 = (v2){_e.x, _e.y}; H##9 = (v2){_e.z, _e.w}; }

__global__ __launch_bounds__(NTHREADS)
__attribute__((amdgpu_waves_per_eu(1, 2)))
void rnn2_fused(const float* __restrict__ x,        // [B,T,1]
                const float* __restrict__ hidden,   // [2,B,H]
                const float* __restrict__ W_ih0,    // [H,1]
                const float* __restrict__ W_hh0,    // [H,H]
                const float* __restrict__ b_ih0,    // [H]
                const float* __restrict__ b_hh0,    // [H]
                const float* __restrict__ W_ih1,    // [H,H]
                const float* __restrict__ W_hh1,    // [H,H]
                const float* __restrict__ b_ih1,    // [H]
                const float* __restrict__ b_hh1,    // [H]
                const float* __restrict__ fc_w,     // [1,H]
                const float* __restrict__ fc_b,     // [1]
                float* __restrict__ out)            // [B] ++ [2,B,H] flat
{
    const int tid = threadIdx.x;
    int g = tid / Hn;                  // 0..3
    int j = tid - g * Hn;              // 0..19 (0..3 for tid>=60)
    const bool lane_ok = (tid < GB * Hn);
    if (!lane_ok) g = GB - 1;          // lanes 60..63 dup batch 2, j=0..3
                                       // (same-addr same-data writes: benign)
    const int  b        = blockIdx.x * GB + g;
    const bool b_ok     = (b < Bsz);
    const int  bl       = b_ok ? b : (Bsz - 1);
    const bool store_ok = lane_ok && b_ok;

    __shared__ float xs[GB][XPAD];     // 6.24 KB
    __shared__ float hs[2][GB][Hn];    // single-buffer state [layer][g][j]

    // ---- per-lane weight rows as 30 named v2 SSA values (loop-invariant)
    LOAD_ROWP(w0, W_hh0 + j * Hn)      // layer0 recurrent row j
    LOAD_ROWP(w1, W_ih1 + j * Hn)      // layer1 input row j
    LOAD_ROWP(w2, W_hh1 + j * Hn)      // layer1 recurrent row j

    const float wih0  = W_ih0[j];
    const float bias0 = b_ih0[j] + b_hh0[j];
    const float bias1 = b_ih1[j] + b_hh1[j];

    // ---- stage ALL x (coalesced float4; clamped batch rows)
    {
        const int bB = blockIdx.x * GB;
        #pragma unroll
        for (int r = 0; r < (GB * Tn) / (NTHREADS * 4); ++r) {  // 6 rounds
            const int c  = (r * NTHREADS + tid) * 4;
            const int gg = c >> 9;            // c / 512
            const int t  = c & (Tn - 1);      // c % 512
            const int bb = (bB + gg < Bsz) ? (bB + gg) : (Bsz - 1);
            float4 v = *(const float4*)(x + (long)bb * Tn + t);
            *(float4*)&xs[gg][t] = v;
        }
    }

    // ---- init state: hs[0] = h0[-1], hs[1] = h1[-1]
    hs[0][g][j] = hidden[bl * Hn + j];
    hs[1][g][j] = hidden[(long)Bsz * Hn + bl * Hn + j];
    // single-wave in-order DS pipe: later reads see these writes

    // ---- prologue (i=0): h0[0] = tanh(W_hh0 h0[-1] + x0 wih0 + b0)
    {
        READ_H(hA, &hs[0][g][0])
        v2 a0  = (v2){fmaf(xs[g][0], wih0, bias0), 0.f};
        v2 a0b = (v2){0.f, 0.f};
        DOT20P(a0, a0b, w0, hA);
        v2 s0 = a0 + a0b;
        hs[0][g][j] = tanh_fast(s0.x + s0.y);
    }

    // ---- main loop i=1..511: entry: hs[0]=h0[i-1], hs[1]=h1[i-2].
    // computes h0[i], h1[i-1]; writes both. UNROLL 4: cross-iteration
    // scheduling window (layer1(i) overlaps layer0(i+1)'s LDS latency).
    #pragma unroll 4
    for (int i = 1; i < Tn; ++i) {
        READ_H(hA, &hs[0][g][0])
        READ_H(hB, &hs[1][g][0])

        const float xt = xs[g][i];

        v2 a0  = (v2){fmaf(xt, wih0, bias0), 0.f};
        v2 a0b = (v2){0.f, 0.f};
        v2 a1  = (v2){bias1, 0.f};
        v2 a1b = (v2){0.f, 0.f};
        v2 a2  = (v2){0.f, 0.f};
        v2 a2b = (v2){0.f, 0.f};
        DOT20P(a0, a0b, w0, hA);
        DOT20P(a1, a1b, w1, hA);
        DOT20P(a2, a2b, w2, hB);

        const v2 s0 = a0 + a0b;
        const v2 s1 = (a1 + a1b) + (a2 + a2b);
        const float n0 = tanh_fast(s0.x + s0.y);
        const float n1 = tanh_fast(s1.x + s1.y);
        hs[0][g][j] = n0;   // h0[i]
        hs[1][g][j] = n1;   // h1[i-1]
    }

    // ---- epilogue (i=512): h1[511] from h0[511], h1[510]
    {
        READ_H(hA, &hs[0][g][0])
        READ_H(hB, &hs[1][g][0])
        v2 a1  = (v2){bias1, 0.f};
        v2 a1b = (v2){0.f, 0.f};
        v2 a2  = (v2){0.f, 0.f};
        v2 a2b = (v2){0.f, 0.f};
        DOT20P(a1, a1b, w1, hA);
        DOT20P(a2, a2b, w2, hB);
        const v2 s1 = (a1 + a1b) + (a2 + a2b);
        hs[1][g][j] = tanh_fast(s1.x + s1.y);
    }

    // ---- outputs: hs[0]=h0[511], hs[1]=h1[511]
    if (store_ok) {
        out[Bsz + (long)b * Hn + j]                  = hs[0][g][j];  // new_hidden[0]
        out[Bsz + (long)Bsz * Hn + (long)b * Hn + j] = hs[1][g][j];  // new_hidden[1]
        if (j == 0) {                  // fc head: one lane per batch
            LOAD_ROWP(fw, fc_w)
            READ_H(hv, &hs[1][g][0])
            v2 aA = (v2){fc_b[0], 0.f};
            v2 aB = (v2){0.f, 0.f};
            DOT20P(aA, aB, fw, hv);
            const v2 s = aA + aB;
            out[b] = s.x + s.y;
        }
    }
}

extern "C" void kernel_launch(void* const* d_in, const int* in_sizes, int n_in,
                              void* d_out, int out_size, void* d_ws, size_t ws_size,
                              hipStream_t stream) {
    const float* x      = (const float*)d_in[0];
    const float* hidden = (const float*)d_in[1];
    const float* W_ih0  = (const float*)d_in[2];
    const float* W_hh0  = (const float*)d_in[3];
    const float* b_ih0  = (const float*)d_in[4];
    const float* b_hh0  = (const float*)d_in[5];
    const float* W_ih1  = (const float*)d_in[6];
    const float* W_hh1  = (const float*)d_in[7];
    const float* b_ih1  = (const float*)d_in[8];
    const float* b_hh1  = (const float*)d_in[9];
    const float* fc_w   = (const float*)d_in[10];
    const float* fc_b   = (const float*)d_in[11];

    const int nblocks = (Bsz + GB - 1) / GB;   // 1366
    rnn2_fused<<<nblocks, NTHREADS, 0, stream>>>(
        x, hidden, W_ih0, W_hh0, b_ih0, b_hh0,
        W_ih1, W_hh1, b_ih1, b_hh1, fc_w, fc_b, (float*)d_out);
}